// Round 17
// baseline (863.758 us; speedup 1.0000x reference)
//
#include <hip/hip_runtime.h>
#include <hip/hip_bf16.h>

typedef unsigned short ushort_t;
typedef __attribute__((ext_vector_type(8))) short short8;
typedef __attribute__((ext_vector_type(4))) float f32x4;
typedef __attribute__((ext_vector_type(16))) float f32x16;
typedef __attribute__((ext_vector_type(2))) int v2i;
typedef __attribute__((ext_vector_type(4))) int i32x4;

#define SEQ 4096
#define EMB 1024
#define HEADS 16
#define DH 128
#define SCALE_LOG2E 0.12751743f           /* (1/sqrt(128)) * log2(e): scores in log2 domain */

__device__ __forceinline__ ushort_t f2bf(float f) {
    union { float f; unsigned u; } v; v.f = f;
    unsigned r = v.u + 0x7fffu + ((v.u >> 16) & 1u);
    return (ushort_t)(r >> 16);
}

__device__ __forceinline__ int cvt_pk_bf16(float lo, float hi) {
    int r;
    asm("v_cvt_pk_bf16_f32 %0, %1, %2" : "=v"(r) : "v"(lo), "v"(hi));
    return r;
}

__device__ __forceinline__ float exp2_raw(float x) {
    float r;
    asm("v_exp_f32 %0, %1" : "=v"(r) : "v"(x));
    return r;
}

// cross 32-lane-half combine: every lane gets op(x[l], x[l^32])
__device__ __forceinline__ float cross32_max(float x) {
    v2i r = __builtin_amdgcn_permlane32_swap(__float_as_int(x), __float_as_int(x), false, false);
    return fmaxf(__int_as_float(r.x), __int_as_float(r.y));
}
__device__ __forceinline__ float cross32_add(float x) {
    v2i r = __builtin_amdgcn_permlane32_swap(__float_as_int(x), __float_as_int(x), false, false);
    return __int_as_float(r.x) + __int_as_float(r.y);
}

// async global->LDS, 16B per lane; lds base must be wave-uniform (dest = base + lane*16)
__device__ __forceinline__ void gload_lds16(const ushort_t* g, ushort_t* l) {
    __builtin_amdgcn_global_load_lds(
        (const __attribute__((address_space(1))) void*)g,
        (__attribute__((address_space(3))) void*)l, 16, 0, 0);
}

// xp = x + positional_encoding, bf16 out. One block per row; thread handles 4 cols.
// For c >= 10: 10000^expo overflows fp32 -> denom 0 -> pe = (c odd ? 1 : 0) exactly.
__global__ __launch_bounds__(256) void prep_x_kernel(
    const float* __restrict__ x, ushort_t* __restrict__ xp)
{
    const int s = blockIdx.x;
    const int c0 = threadIdx.x * 4;
    const float4 v = *(const float4*)(x + (size_t)s * EMB + c0);
    float pe[4];
    if (c0 >= 10) {
        pe[0] = 0.f; pe[1] = 1.f; pe[2] = 0.f; pe[3] = 1.f;
    } else {
#pragma unroll
        for (int i = 0; i < 4; ++i) {
            const int c = c0 + i;
            float p = powf(10000.0f, (float)(c & ~1));
            float ang = (float)s * ((float)EMB / p);      // inf -> 0 (matches jax fp32)
            pe[i] = (c & 1) ? cosf(ang) : sinf(ang);
        }
    }
    union { ushort_t u[4]; unsigned long long ll; } o;
    o.u[0] = f2bf(v.x + pe[0]); o.u[1] = f2bf(v.y + pe[1]);
    o.u[2] = f2bf(v.z + pe[2]); o.u[3] = f2bf(v.w + pe[3]);
    *(unsigned long long*)(xp + (size_t)s * EMB + c0) = o.ll;
}

// Fused Wq/Wk/Wv transpose: W[h][k][n] f32 -> Wt[(which*16+h)][n][k] bf16 (contiguous dest).
__global__ __launch_bounds__(256) void transpose_qkv_kernel(
    const float* __restrict__ Wq, const float* __restrict__ Wk,
    const float* __restrict__ Wv, ushort_t* __restrict__ Wt)
{
    const int z = blockIdx.z;
    const int which = z >> 4, b = z & 15;
    const float* W = (which == 0) ? Wq : (which == 1) ? Wk : Wv;
    const int k0 = blockIdx.x * 64, n0 = blockIdx.y * 64;
    const int tx = threadIdx.x & 63, ty = threadIdx.x >> 6;
    __shared__ ushort_t t[64][65];
    const float* Wb = W + (size_t)b * EMB * DH;
    ushort_t* Wtb = Wt + (size_t)z * DH * EMB;
#pragma unroll
    for (int i = 0; i < 16; ++i) {
        const int r = ty + i * 4;
        t[r][tx] = f2bf(Wb[(size_t)(k0 + r) * DH + n0 + tx]);
    }
    __syncthreads();
#pragma unroll
    for (int i = 0; i < 16; ++i) {
        const int r = ty + i * 4;
        Wtb[(size_t)(n0 + r) * EMB + k0 + tx] = t[tx][r];
    }
}

// W[b][k][n] f32 -> Wt[b][n][k] bf16, coalesced via 64x64 LDS tile (used for Wo)
__global__ __launch_bounds__(256) void transpose_w_kernel(
    const float* __restrict__ W, ushort_t* __restrict__ Wt, int Kd, int Nd)
{
    const int b = blockIdx.z;
    const int k0 = blockIdx.x * 64, n0 = blockIdx.y * 64;
    const int tx = threadIdx.x & 63, ty = threadIdx.x >> 6;
    __shared__ ushort_t t[64][65];
    const float* Wb = W + (size_t)b * Kd * Nd;
    ushort_t* Wtb = Wt + (size_t)b * Nd * Kd;
#pragma unroll
    for (int i = 0; i < 16; ++i) {
        const int r = ty + i * 4;
        t[r][tx] = f2bf(Wb[(size_t)(k0 + r) * Nd + n0 + tx]);
    }
    __syncthreads();
#pragma unroll
    for (int i = 0; i < 16; ++i) {
        const int r = ty + i * 4;
        Wtb[(size_t)(n0 + r) * Kd + k0 + tx] = t[tx][r];
    }
}

// C = A(bf16, MxK) @ Bt(bf16, NxK)^T + bias, 128x128 tile, 4 waves (2x2), BK=32.
// MODE 0: A shared, Bt per-head; bias[h*N+col]; bf16 out [(h*M+row)*N+col]   (K)
// MODE 4: like MODE 0 but out scaled by SCALE_LOG2E                           (Q)
// MODE 3: A per-head, Bt shared;  bias[h*M+row]; bf16 out [(h*M+row)*N+col]  (V^T)
// MODE 2: batch=1; f32 out [row*N+col]                                       (final)
template <int MODE>
__global__ __launch_bounds__(256) void gemm_bias_kernel(
    const ushort_t* __restrict__ A, const ushort_t* __restrict__ Bt,
    const float* __restrict__ bias, void* __restrict__ Cout,
    int M, int N, int K)
{
    const int mb = blockIdx.x, nb = blockIdx.y, h = blockIdx.z;
    const int tid = threadIdx.x;
    const int w = tid >> 6;
    const int l = tid & 63;
    const int l15 = l & 15, lhi = l >> 4;
    const int wm = w >> 1, wn = w & 1;

    __shared__ ushort_t Abuf[2][128 * 32];
    __shared__ ushort_t Bbuf[2][128 * 32];

    const ushort_t* Ah = (MODE == 3) ? A + (size_t)h * M * K : A;
    const ushort_t* Bh = (MODE == 0 || MODE == 4) ? Bt + (size_t)h * N * K : Bt;

    const int m0 = mb * 128, n0 = nb * 128;

    f32x4 acc[4][4];
#pragma unroll
    for (int f = 0; f < 4; ++f)
#pragma unroll
        for (int g = 0; g < 4; ++g) acc[f][g] = f32x4{0.f, 0.f, 0.f, 0.f};

    const int srow = w * 16 + (l >> 2);
    const int sk = (l & 3) * 8;
    auto stage = [&](int buf, int kt) {
        const int k0 = kt * 32;
#pragma unroll
        for (int i = 0; i < 2; ++i) {
            gload_lds16(Ah + (size_t)(m0 + i * 64 + srow) * K + k0 + sk,
                        &Abuf[buf][(i * 64 + w * 16) * 32]);
            gload_lds16(Bh + (size_t)(n0 + i * 64 + srow) * K + k0 + sk,
                        &Bbuf[buf][(i * 64 + w * 16) * 32]);
        }
    };

    const int nk = K / 32;
    int cur = 0;
    stage(0, 0);
    asm volatile("s_waitcnt vmcnt(0)" ::: "memory");
    __syncthreads();

    for (int kt = 0; kt < nk; ++kt) {
        if (kt + 1 < nk) stage(cur ^ 1, kt + 1);

        short8 af[4], bf[4];
#pragma unroll
        for (int f = 0; f < 4; ++f)
            af[f] = *(const short8*)(&Abuf[cur][(wm * 64 + f * 16 + l15) * 32 + lhi * 8]);
#pragma unroll
        for (int g = 0; g < 4; ++g)
            bf[g] = *(const short8*)(&Bbuf[cur][(wn * 64 + g * 16 + l15) * 32 + lhi * 8]);
#pragma unroll
        for (int f = 0; f < 4; ++f)
#pragma unroll
            for (int g = 0; g < 4; ++g)
                acc[f][g] = __builtin_amdgcn_mfma_f32_16x16x32_bf16(af[f], bf[g], acc[f][g], 0, 0, 0);

        asm volatile("s_waitcnt vmcnt(0)" ::: "memory");
        __syncthreads();
        cur ^= 1;
    }

#pragma unroll
    for (int f = 0; f < 4; ++f) {
        const int row0 = m0 + wm * 64 + f * 16 + 4 * lhi;
#pragma unroll
        for (int g = 0; g < 4; ++g) {
            const int col = n0 + wn * 64 + g * 16 + l15;
            float bv;
            if (MODE == 0 || MODE == 4) bv = bias[(size_t)h * N + col];
            else if (MODE == 3) bv = 0.f;
            else bv = bias[col];
#pragma unroll
            for (int r = 0; r < 4; ++r) {
                const int row = row0 + r;
                float val = acc[f][g][r];
                if (MODE == 3) val += bias[(size_t)h * M + row];
                else val += bv;
                if (MODE == 4) val *= SCALE_LOG2E;
                if (MODE == 2)
                    ((float*)Cout)[(size_t)row * N + col] = val;
                else
                    ((ushort_t*)Cout)[((size_t)h * M + row) * N + col] = f2bf(val);
            }
        }
    }
}

// Flash attention, 32x32 swapped-operand, log2 softmax, XCD-chunked swizzle.
// Block: 4 waves x 32 q = 128 q-rows. KVBLK=64.
// LDS = 2*16K (K dbuf) + 1*16K (V single buf) = 48 KB -> 3 blocks/CU (TLP probe).
// Pipeline: barrier1 -> stage K(t+2) -> QK^T(t+1) -> softmax(t) -> PV(t)
//           -> barrier2 -> stage V(t+1) (latency absorbed by co-resident blocks).
__global__ __launch_bounds__(256, 3) void attn_kernel(
    const ushort_t* __restrict__ Q, const ushort_t* __restrict__ K,
    const ushort_t* __restrict__ Vt, ushort_t* __restrict__ att)
{
    // XCD swizzle: 512 blocks, 8 XCDs, 64 blocks/XCD; major index = head pair
    const int bid = blockIdx.x;
    const int swz = (bid & 7) * 64 + (bid >> 3);   // bijective (512 % 8 == 0)
    const int qb = swz & 31;
    const int h = swz >> 5;

    const int tid = threadIdx.x;
    const int w = tid >> 6;
    const int l = tid & 63;
    const int l31 = l & 31;
    const int hi = l >> 5;

    __shared__ ushort_t Kbuf[2][64 * 128];   // [t][d], double-buffered
    __shared__ ushort_t Vbuf[128 * 64];      // [d][t], single-buffered

    const ushort_t* Qh = Q + (size_t)h * SEQ * DH;
    const ushort_t* Kh = K + (size_t)h * SEQ * DH;
    const ushort_t* Vh = Vt + (size_t)h * DH * SEQ;

    const int qrow = qb * 128 + w * 32 + l31;
    short8 qf[8];
#pragma unroll
    for (int c = 0; c < 8; ++c)
        qf[c] = *(const short8*)(Qh + (size_t)qrow * DH + c * 16 + hi * 8);

    f32x16 o[4];
#pragma unroll
    for (int dblk = 0; dblk < 4; ++dblk)
#pragma unroll
        for (int i = 0; i < 16; ++i) o[dblk][i] = 0.f;
    float mrun = -1e30f, lrun = 0.f;

    auto stage_k = [&](int buf, int t0) {
#pragma unroll
        for (int i = 0; i < 4; ++i) {
            const int L = i * 256 + tid;
            const int row = L >> 4;
            const int c = (L & 15) ^ ((row ^ (row >> 3)) & 15);
            gload_lds16(Kh + (size_t)(t0 + row) * DH + c * 8,
                        &Kbuf[buf][(L & ~63) * 8]);
        }
    };
    auto stage_v = [&](int t0) {
#pragma unroll
        for (int i = 0; i < 4; ++i) {
            const int L = i * 256 + tid;
            const int row = L >> 3;
            const int c = (L & 7) ^ ((row ^ (row >> 3)) & 7);
            gload_lds16(Vh + (size_t)row * SEQ + t0 + c * 8,
                        &Vbuf[(L & ~63) * 8]);
        }
    };

    const int kmsk0 = (l31 ^ (l31 >> 3)) & 15;
    const int r1row = 32 + l31;
    const int kmsk1 = (r1row ^ (r1row >> 3)) & 15;

    // prologue: tile 0 (K+V) landed; K(1) in flight; QK^T(0) computed
    stage_k(0, 0); stage_v(0);
    asm volatile("s_waitcnt vmcnt(0)" ::: "memory");
    __syncthreads();
    stage_k(1, 64);

    f32x16 pP0, pP1, pN0, pN1;
#pragma unroll
    for (int i = 0; i < 16; ++i) { pP0[i] = 0.f; pP1[i] = 0.f; pN0[i] = 0.f; pN1[i] = 0.f; }
    __builtin_amdgcn_s_setprio(1);
#pragma unroll
    for (int c = 0; c < 8; ++c) {
        short8 k0 = *(const short8*)(&Kbuf[0][l31 * 128 + ((c * 2 + hi) ^ kmsk0) * 8]);
        pP0 = __builtin_amdgcn_mfma_f32_32x32x16_bf16(k0, qf[c], pP0, 0, 0, 0);
        short8 k1 = *(const short8*)(&Kbuf[0][r1row * 128 + ((c * 2 + hi) ^ kmsk1) * 8]);
        pP1 = __builtin_amdgcn_mfma_f32_32x32x16_bf16(k1, qf[c], pP1, 0, 0, 0);
    }
    __builtin_amdgcn_s_setprio(0);

    const int NT = SEQ / 64;
    for (int t = 0; t < NT; ++t) {
        asm volatile("s_waitcnt vmcnt(0)" ::: "memory");   // K(t+1) + V(t) landed
        __syncthreads();                                    // all waves past PV(t-1)

        if (t + 2 < NT) stage_k(t & 1, (t + 2) * 64);      // full iteration to land

        if (t + 1 < NT) {
            // QK^T(t+1) -> pN (MFMA; overlaps softmax(t) VALU below)
#pragma unroll
            for (int i = 0; i < 16; ++i) { pN0[i] = 0.f; pN1[i] = 0.f; }
            __builtin_amdgcn_s_setprio(1);
#pragma unroll
            for (int c = 0; c < 8; ++c) {
                short8 k0 = *(const short8*)(&Kbuf[(t + 1) & 1][l31 * 128 + ((c * 2 + hi) ^ kmsk0) * 8]);
                pN0 = __builtin_amdgcn_mfma_f32_32x32x16_bf16(k0, qf[c], pN0, 0, 0, 0);
                short8 k1 = *(const short8*)(&Kbuf[(t + 1) & 1][r1row * 128 + ((c * 2 + hi) ^ kmsk1) * 8]);
                pN1 = __builtin_amdgcn_mfma_f32_32x32x16_bf16(k1, qf[c], pN1, 0, 0, 0);
            }
            __builtin_amdgcn_s_setprio(0);
        }

        // ---- softmax(t) on pP (VALU; log2 domain); max via v_max3 nests ----
        float m16[16];
#pragma unroll
        for (int i = 0; i < 16; ++i) m16[i] = fmaxf(pP0[i], pP1[i]);
        float t6[6];
#pragma unroll
        for (int i = 0; i < 5; ++i)
            t6[i] = fmaxf(fmaxf(m16[3 * i], m16[3 * i + 1]), m16[3 * i + 2]);
        t6[5] = m16[15];
        float u0 = fmaxf(fmaxf(t6[0], t6[1]), t6[2]);
        float u1 = fmaxf(fmaxf(t6[3], t6[4]), t6[5]);
        float mx = cross32_max(fmaxf(u0, u1));

        const float mnew = fmaxf(mrun, mx);
        if (!__all(mx - mrun <= 8.0f)) {     // defer-max (THR=8 in log2 units)
            const float corr = exp2_raw(mrun - mnew);
            lrun *= corr;
#pragma unroll
            for (int dblk = 0; dblk < 4; ++dblk)
#pragma unroll
                for (int i = 0; i < 16; ++i) o[dblk][i] *= corr;
            mrun = mnew;
        }
#pragma unroll
        for (int i = 0; i < 16; ++i) { pP0[i] = exp2_raw(pP0[i] - mrun); pP1[i] = exp2_raw(pP1[i] - mrun); }
        float s16[16];
#pragma unroll
        for (int i = 0; i < 16; ++i) s16[i] = pP0[i] + pP1[i];
        float s8[8];
#pragma unroll
        for (int i = 0; i < 8; ++i) s8[i] = s16[2 * i] + s16[2 * i + 1];
        float s4[4];
#pragma unroll
        for (int i = 0; i < 4; ++i) s4[i] = s8[2 * i] + s8[2 * i + 1];
        float ps = (s4[0] + s4[1]) + (s4[2] + s4[3]);
        lrun += cross32_add(ps);

        // P -> bf16 PV A-fragments (T12): swap(A_,C_) = (w0,w2), swap(B_,D_) = (w1,w3)
        short8 pa[4];
#pragma unroll
        for (int b = 0; b < 4; ++b) {
            const int r0 = (b & 1) * 8;
            const float* psrc = (b < 2) ? (const float*)&pP0 : (const float*)&pP1;
            const int A_ = cvt_pk_bf16(psrc[r0 + 0], psrc[r0 + 1]);
            const int B_ = cvt_pk_bf16(psrc[r0 + 2], psrc[r0 + 3]);
            const int C_ = cvt_pk_bf16(psrc[r0 + 4], psrc[r0 + 5]);
            const int D_ = cvt_pk_bf16(psrc[r0 + 6], psrc[r0 + 7]);
            v2i s1 = __builtin_amdgcn_permlane32_swap(A_, C_, false, false);
            v2i s2 = __builtin_amdgcn_permlane32_swap(B_, D_, false, false);
            i32x4 wv; wv.x = s1.x; wv.y = s2.x; wv.z = s1.y; wv.w = s2.y;
            pa[b] = __builtin_bit_cast(short8, wv);
        }

        // ---- PV(t): O^T[d][q] += Vt[d][t] P[t][q] ----
        __builtin_amdgcn_s_setprio(1);
#pragma unroll
        for (int dblk = 0; dblk < 4; ++dblk) {
            const int vrow = dblk * 32 + l31;
            const int vmsk = (vrow ^ (vrow >> 3)) & 7;
#pragma unroll
            for (int ks = 0; ks < 4; ++ks) {
                const int ch = ((ks * 2 + hi) ^ vmsk) * 8;
                short8 vv = *(const short8*)(&Vbuf[vrow * 64 + ch]);
                o[dblk] = __builtin_amdgcn_mfma_f32_32x32x16_bf16(vv, pa[ks], o[dblk], 0, 0, 0);
            }
        }
        __builtin_amdgcn_s_setprio(0);

        __syncthreads();                    // all waves done reading Vbuf
        if (t + 1 < NT) stage_v((t + 1) * 64);   // single-buffer refill

        pP0 = pN0; pP1 = pN1;
    }

    // epilogue: att[q][h*128+d] = O^T[d][q]/lrun ; d = dblk*32 + (2j&3)+8*(j>>1)+4*hi
    const float inv = 1.0f / lrun;
    ushort_t* arow = att + (size_t)qrow * (HEADS * DH) + h * DH;
#pragma unroll
    for (int dblk = 0; dblk < 4; ++dblk)
#pragma unroll
        for (int j = 0; j < 8; ++j) {
            const int d = dblk * 32 + ((2 * j) & 3) + 8 * (j >> 1) + 4 * hi;
            const int pk = cvt_pk_bf16(o[dblk][2 * j] * inv, o[dblk][2 * j + 1] * inv);
            *(int*)(arow + d) = pk;
        }
}

extern "C" void kernel_launch(void* const* d_in, const int* in_sizes, int n_in,
                              void* d_out, int out_size, void* d_ws, size_t ws_size,
                              hipStream_t stream) {
    const float* x  = (const float*)d_in[0];
    const float* Wq = (const float*)d_in[1];
    const float* bq = (const float*)d_in[2];
    const float* Wk = (const float*)d_in[3];
    const float* bk = (const float*)d_in[4];
    const float* Wv = (const float*)d_in[5];
    const float* bv = (const float*)d_in[6];
    const float* Wo = (const float*)d_in[7];
    const float* bo = (const float*)d_in[8];
    float* out = (float*)d_out;

    ushort_t* ws = (ushort_t*)d_ws;
    ushort_t* xp   = ws;
    ushort_t* Wqt  = xp  + (size_t)SEQ * EMB;        // Wqt, Wkt, Wvt contiguous
    ushort_t* Wkt  = Wqt + (size_t)HEADS * DH * EMB;
    ushort_t* Wvt  = Wkt + (size_t)HEADS * DH * EMB;
    ushort_t* Wot  = Wvt + (size_t)HEADS * DH * EMB;
    ushort_t* Qb   = Wot + (size_t)EMB * (HEADS * DH);
    ushort_t* Kb   = Qb  + (size_t)HEADS * SEQ * DH;
    ushort_t* Vtb  = Kb  + (size_t)HEADS * SEQ * DH;
    ushort_t* attb = Vtb + (size_t)HEADS * SEQ * DH;

    prep_x_kernel<<<dim3(SEQ), 256, 0, stream>>>(x, xp);

    transpose_qkv_kernel<<<dim3(EMB / 64, DH / 64, 48), 256, 0, stream>>>(Wq, Wk, Wv, Wqt);
    transpose_w_kernel<<<dim3((HEADS * DH) / 64, EMB / 64, 1), 256, 0, stream>>>(Wo, Wot, HEADS * DH, EMB);

    // Q pre-scaled by SCALE*log2e; K normal; V computed transposed [h][d][s]
    gemm_bias_kernel<4><<<dim3(SEQ / 128, DH / 128, HEADS), 256, 0, stream>>>(xp, Wqt, bq, Qb, SEQ, DH, EMB);
    gemm_bias_kernel<0><<<dim3(SEQ / 128, DH / 128, HEADS), 256, 0, stream>>>(xp, Wkt, bk, Kb, SEQ, DH, EMB);
    gemm_bias_kernel<3><<<dim3(DH / 128, SEQ / 128, HEADS), 256, 0, stream>>>(Wvt, xp, bv, Vtb, DH, SEQ, EMB);

    attn_kernel<<<dim3(SEQ / 128 * HEADS), 256, 0, stream>>>(Qb, Kb, Vtb, attb);

    gemm_bias_kernel<2><<<dim3(SEQ / 128, EMB / 128, 1), 256, 0, stream>>>(attb, Wot, bo, out, SEQ, EMB, HEADS * DH);
}

// Round 18
// 380.750 us; speedup vs baseline: 2.2686x; 2.2686x over previous
//
#include <hip/hip_runtime.h>
#include <hip/hip_bf16.h>

typedef unsigned short ushort_t;
typedef __attribute__((ext_vector_type(8))) short short8;
typedef __attribute__((ext_vector_type(4))) float f32x4;
typedef __attribute__((ext_vector_type(16))) float f32x16;
typedef __attribute__((ext_vector_type(2))) int v2i;
typedef __attribute__((ext_vector_type(4))) int i32x4;

#define SEQ 4096
#define EMB 1024
#define HEADS 16
#define DH 128
#define SCALE_LOG2E 0.12751743f           /* (1/sqrt(128)) * log2(e): scores in log2 domain */

__device__ __forceinline__ ushort_t f2bf(float f) {
    union { float f; unsigned u; } v; v.f = f;
    unsigned r = v.u + 0x7fffu + ((v.u >> 16) & 1u);
    return (ushort_t)(r >> 16);
}

__device__ __forceinline__ int cvt_pk_bf16(float lo, float hi) {
    int r;
    asm("v_cvt_pk_bf16_f32 %0, %1, %2" : "=v"(r) : "v"(lo), "v"(hi));
    return r;
}

__device__ __forceinline__ float exp2_raw(float x) {
    float r;
    asm("v_exp_f32 %0, %1" : "=v"(r) : "v"(x));
    return r;
}

// cross 32-lane-half combine: every lane gets op(x[l], x[l^32])
__device__ __forceinline__ float cross32_max(float x) {
    v2i r = __builtin_amdgcn_permlane32_swap(__float_as_int(x), __float_as_int(x), false, false);
    return fmaxf(__int_as_float(r.x), __int_as_float(r.y));
}
__device__ __forceinline__ float cross32_add(float x) {
    v2i r = __builtin_amdgcn_permlane32_swap(__float_as_int(x), __float_as_int(x), false, false);
    return __int_as_float(r.x) + __int_as_float(r.y);
}

// async global->LDS, 16B per lane; lds base must be wave-uniform (dest = base + lane*16)
__device__ __forceinline__ void gload_lds16(const ushort_t* g, ushort_t* l) {
    __builtin_amdgcn_global_load_lds(
        (const __attribute__((address_space(1))) void*)g,
        (__attribute__((address_space(3))) void*)l, 16, 0, 0);
}

// xp = x + positional_encoding, bf16 out. One block per row; thread handles 4 cols.
// For c >= 10: 10000^expo overflows fp32 -> denom 0 -> pe = (c odd ? 1 : 0) exactly.
__global__ __launch_bounds__(256) void prep_x_kernel(
    const float* __restrict__ x, ushort_t* __restrict__ xp)
{
    const int s = blockIdx.x;
    const int c0 = threadIdx.x * 4;
    const float4 v = *(const float4*)(x + (size_t)s * EMB + c0);
    float pe[4];
    if (c0 >= 10) {
        pe[0] = 0.f; pe[1] = 1.f; pe[2] = 0.f; pe[3] = 1.f;
    } else {
#pragma unroll
        for (int i = 0; i < 4; ++i) {
            const int c = c0 + i;
            float p = powf(10000.0f, (float)(c & ~1));
            float ang = (float)s * ((float)EMB / p);      // inf -> 0 (matches jax fp32)
            pe[i] = (c & 1) ? cosf(ang) : sinf(ang);
        }
    }
    union { ushort_t u[4]; unsigned long long ll; } o;
    o.u[0] = f2bf(v.x + pe[0]); o.u[1] = f2bf(v.y + pe[1]);
    o.u[2] = f2bf(v.z + pe[2]); o.u[3] = f2bf(v.w + pe[3]);
    *(unsigned long long*)(xp + (size_t)s * EMB + c0) = o.ll;
}

// Fused Wq/Wk/Wv transpose: W[h][k][n] f32 -> Wt[(which*16+h)][n][k] bf16 (contiguous dest).
__global__ __launch_bounds__(256) void transpose_qkv_kernel(
    const float* __restrict__ Wq, const float* __restrict__ Wk,
    const float* __restrict__ Wv, ushort_t* __restrict__ Wt)
{
    const int z = blockIdx.z;
    const int which = z >> 4, b = z & 15;
    const float* W = (which == 0) ? Wq : (which == 1) ? Wk : Wv;
    const int k0 = blockIdx.x * 64, n0 = blockIdx.y * 64;
    const int tx = threadIdx.x & 63, ty = threadIdx.x >> 6;
    __shared__ ushort_t t[64][65];
    const float* Wb = W + (size_t)b * EMB * DH;
    ushort_t* Wtb = Wt + (size_t)z * DH * EMB;
#pragma unroll
    for (int i = 0; i < 16; ++i) {
        const int r = ty + i * 4;
        t[r][tx] = f2bf(Wb[(size_t)(k0 + r) * DH + n0 + tx]);
    }
    __syncthreads();
#pragma unroll
    for (int i = 0; i < 16; ++i) {
        const int r = ty + i * 4;
        Wtb[(size_t)(n0 + r) * EMB + k0 + tx] = t[tx][r];
    }
}

// W[b][k][n] f32 -> Wt[b][n][k] bf16, coalesced via 64x64 LDS tile (used for Wo)
__global__ __launch_bounds__(256) void transpose_w_kernel(
    const float* __restrict__ W, ushort_t* __restrict__ Wt, int Kd, int Nd)
{
    const int b = blockIdx.z;
    const int k0 = blockIdx.x * 64, n0 = blockIdx.y * 64;
    const int tx = threadIdx.x & 63, ty = threadIdx.x >> 6;
    __shared__ ushort_t t[64][65];
    const float* Wb = W + (size_t)b * Kd * Nd;
    ushort_t* Wtb = Wt + (size_t)b * Nd * Kd;
#pragma unroll
    for (int i = 0; i < 16; ++i) {
        const int r = ty + i * 4;
        t[r][tx] = f2bf(Wb[(size_t)(k0 + r) * Nd + n0 + tx]);
    }
    __syncthreads();
#pragma unroll
    for (int i = 0; i < 16; ++i) {
        const int r = ty + i * 4;
        Wtb[(size_t)(n0 + r) * Kd + k0 + tx] = t[tx][r];
    }
}

// C = A(bf16, MxK) @ Bt(bf16, NxK)^T + bias, 128x128 tile, 4 waves (2x2), BK=32.
// MODE 0: A shared, Bt per-head; bias[h*N+col]; bf16 out [(h*M+row)*N+col]   (K)
// MODE 4: like MODE 0 but out scaled by SCALE_LOG2E                           (Q)
// MODE 3: A per-head, Bt shared;  bias[h*M+row]; bf16 out [(h*M+row)*N+col]  (V^T)
// MODE 2: batch=1; f32 out [row*N+col]                                       (final)
template <int MODE>
__global__ __launch_bounds__(256) void gemm_bias_kernel(
    const ushort_t* __restrict__ A, const ushort_t* __restrict__ Bt,
    const float* __restrict__ bias, void* __restrict__ Cout,
    int M, int N, int K)
{
    const int mb = blockIdx.x, nb = blockIdx.y, h = blockIdx.z;
    const int tid = threadIdx.x;
    const int w = tid >> 6;
    const int l = tid & 63;
    const int l15 = l & 15, lhi = l >> 4;
    const int wm = w >> 1, wn = w & 1;

    __shared__ ushort_t Abuf[2][128 * 32];
    __shared__ ushort_t Bbuf[2][128 * 32];

    const ushort_t* Ah = (MODE == 3) ? A + (size_t)h * M * K : A;
    const ushort_t* Bh = (MODE == 0 || MODE == 4) ? Bt + (size_t)h * N * K : Bt;

    const int m0 = mb * 128, n0 = nb * 128;

    f32x4 acc[4][4];
#pragma unroll
    for (int f = 0; f < 4; ++f)
#pragma unroll
        for (int g = 0; g < 4; ++g) acc[f][g] = f32x4{0.f, 0.f, 0.f, 0.f};

    const int srow = w * 16 + (l >> 2);
    const int sk = (l & 3) * 8;
    auto stage = [&](int buf, int kt) {
        const int k0 = kt * 32;
#pragma unroll
        for (int i = 0; i < 2; ++i) {
            gload_lds16(Ah + (size_t)(m0 + i * 64 + srow) * K + k0 + sk,
                        &Abuf[buf][(i * 64 + w * 16) * 32]);
            gload_lds16(Bh + (size_t)(n0 + i * 64 + srow) * K + k0 + sk,
                        &Bbuf[buf][(i * 64 + w * 16) * 32]);
        }
    };

    const int nk = K / 32;
    int cur = 0;
    stage(0, 0);
    asm volatile("s_waitcnt vmcnt(0)" ::: "memory");
    __syncthreads();

    for (int kt = 0; kt < nk; ++kt) {
        if (kt + 1 < nk) stage(cur ^ 1, kt + 1);

        short8 af[4], bf[4];
#pragma unroll
        for (int f = 0; f < 4; ++f)
            af[f] = *(const short8*)(&Abuf[cur][(wm * 64 + f * 16 + l15) * 32 + lhi * 8]);
#pragma unroll
        for (int g = 0; g < 4; ++g)
            bf[g] = *(const short8*)(&Bbuf[cur][(wn * 64 + g * 16 + l15) * 32 + lhi * 8]);
#pragma unroll
        for (int f = 0; f < 4; ++f)
#pragma unroll
            for (int g = 0; g < 4; ++g)
                acc[f][g] = __builtin_amdgcn_mfma_f32_16x16x32_bf16(af[f], bf[g], acc[f][g], 0, 0, 0);

        asm volatile("s_waitcnt vmcnt(0)" ::: "memory");
        __syncthreads();
        cur ^= 1;
    }

#pragma unroll
    for (int f = 0; f < 4; ++f) {
        const int row0 = m0 + wm * 64 + f * 16 + 4 * lhi;
#pragma unroll
        for (int g = 0; g < 4; ++g) {
            const int col = n0 + wn * 64 + g * 16 + l15;
            float bv;
            if (MODE == 0 || MODE == 4) bv = bias[(size_t)h * N + col];
            else if (MODE == 3) bv = 0.f;
            else bv = bias[col];
#pragma unroll
            for (int r = 0; r < 4; ++r) {
                const int row = row0 + r;
                float val = acc[f][g][r];
                if (MODE == 3) val += bias[(size_t)h * M + row];
                else val += bv;
                if (MODE == 4) val *= SCALE_LOG2E;
                if (MODE == 2)
                    ((float*)Cout)[(size_t)row * N + col] = val;
                else
                    ((ushort_t*)Cout)[((size_t)h * M + row) * N + col] = f2bf(val);
            }
        }
    }
}

// Flash attention, 32x32 swapped-operand, log2 softmax, XCD-chunked swizzle.
// Block: 4 waves x 32 q = 128 q-rows. KVBLK=64.
// LDS = 2*16K (K dbuf) + 1*16K (V single buf) = 48 KB -> 3 blocks/CU (TLP probe,
// NO launch-bounds VGPR clamp this time -- r17's (256,3) caused spills).
// Pipeline: barrier1 -> stage K(t+2) -> QK^T(t+1) -> softmax(t) -> PV(t)
//           -> barrier2 -> stage V(t+1) (latency absorbed by co-resident blocks).
__global__ __launch_bounds__(256) void attn_kernel(
    const ushort_t* __restrict__ Q, const ushort_t* __restrict__ K,
    const ushort_t* __restrict__ Vt, ushort_t* __restrict__ att)
{
    // XCD swizzle: 512 blocks, 8 XCDs, 64 blocks/XCD; major index = head pair
    const int bid = blockIdx.x;
    const int swz = (bid & 7) * 64 + (bid >> 3);   // bijective (512 % 8 == 0)
    const int qb = swz & 31;
    const int h = swz >> 5;

    const int tid = threadIdx.x;
    const int w = tid >> 6;
    const int l = tid & 63;
    const int l31 = l & 31;
    const int hi = l >> 5;

    __shared__ ushort_t Kbuf[2][64 * 128];   // [t][d], double-buffered
    __shared__ ushort_t Vbuf[128 * 64];      // [d][t], single-buffered

    const ushort_t* Qh = Q + (size_t)h * SEQ * DH;
    const ushort_t* Kh = K + (size_t)h * SEQ * DH;
    const ushort_t* Vh = Vt + (size_t)h * DH * SEQ;

    const int qrow = qb * 128 + w * 32 + l31;
    short8 qf[8];
#pragma unroll
    for (int c = 0; c < 8; ++c)
        qf[c] = *(const short8*)(Qh + (size_t)qrow * DH + c * 16 + hi * 8);

    f32x16 o[4];
#pragma unroll
    for (int dblk = 0; dblk < 4; ++dblk)
#pragma unroll
        for (int i = 0; i < 16; ++i) o[dblk][i] = 0.f;
    float mrun = -1e30f, lrun = 0.f;

    auto stage_k = [&](int buf, int t0) {
#pragma unroll
        for (int i = 0; i < 4; ++i) {
            const int L = i * 256 + tid;
            const int row = L >> 4;
            const int c = (L & 15) ^ ((row ^ (row >> 3)) & 15);
            gload_lds16(Kh + (size_t)(t0 + row) * DH + c * 8,
                        &Kbuf[buf][(L & ~63) * 8]);
        }
    };
    auto stage_v = [&](int t0) {
#pragma unroll
        for (int i = 0; i < 4; ++i) {
            const int L = i * 256 + tid;
            const int row = L >> 3;
            const int c = (L & 7) ^ ((row ^ (row >> 3)) & 7);
            gload_lds16(Vh + (size_t)row * SEQ + t0 + c * 8,
                        &Vbuf[(L & ~63) * 8]);
        }
    };

    const int kmsk0 = (l31 ^ (l31 >> 3)) & 15;
    const int r1row = 32 + l31;
    const int kmsk1 = (r1row ^ (r1row >> 3)) & 15;

    // prologue: tile 0 (K+V) landed; K(1) in flight; QK^T(0) computed
    stage_k(0, 0); stage_v(0);
    asm volatile("s_waitcnt vmcnt(0)" ::: "memory");
    __syncthreads();
    stage_k(1, 64);

    f32x16 pP0, pP1, pN0, pN1;
#pragma unroll
    for (int i = 0; i < 16; ++i) { pP0[i] = 0.f; pP1[i] = 0.f; pN0[i] = 0.f; pN1[i] = 0.f; }
    __builtin_amdgcn_s_setprio(1);
#pragma unroll
    for (int c = 0; c < 8; ++c) {
        short8 k0 = *(const short8*)(&Kbuf[0][l31 * 128 + ((c * 2 + hi) ^ kmsk0) * 8]);
        pP0 = __builtin_amdgcn_mfma_f32_32x32x16_bf16(k0, qf[c], pP0, 0, 0, 0);
        short8 k1 = *(const short8*)(&Kbuf[0][r1row * 128 + ((c * 2 + hi) ^ kmsk1) * 8]);
        pP1 = __builtin_amdgcn_mfma_f32_32x32x16_bf16(k1, qf[c], pP1, 0, 0, 0);
    }
    __builtin_amdgcn_s_setprio(0);

    const int NT = SEQ / 64;
    for (int t = 0; t < NT; ++t) {
        asm volatile("s_waitcnt vmcnt(0)" ::: "memory");   // K(t+1) + V(t) landed
        __syncthreads();                                    // all waves past PV(t-1)

        if (t + 2 < NT) stage_k(t & 1, (t + 2) * 64);      // full iteration to land

        if (t + 1 < NT) {
            // QK^T(t+1) -> pN (MFMA; overlaps softmax(t) VALU below)
#pragma unroll
            for (int i = 0; i < 16; ++i) { pN0[i] = 0.f; pN1[i] = 0.f; }
            __builtin_amdgcn_s_setprio(1);
#pragma unroll
            for (int c = 0; c < 8; ++c) {
                short8 k0 = *(const short8*)(&Kbuf[(t + 1) & 1][l31 * 128 + ((c * 2 + hi) ^ kmsk0) * 8]);
                pN0 = __builtin_amdgcn_mfma_f32_32x32x16_bf16(k0, qf[c], pN0, 0, 0, 0);
                short8 k1 = *(const short8*)(&Kbuf[(t + 1) & 1][r1row * 128 + ((c * 2 + hi) ^ kmsk1) * 8]);
                pN1 = __builtin_amdgcn_mfma_f32_32x32x16_bf16(k1, qf[c], pN1, 0, 0, 0);
            }
            __builtin_amdgcn_s_setprio(0);
        }

        // ---- softmax(t) on pP (VALU; log2 domain); max via v_max3 nests ----
        float m16[16];
#pragma unroll
        for (int i = 0; i < 16; ++i) m16[i] = fmaxf(pP0[i], pP1[i]);
        float t6[6];
#pragma unroll
        for (int i = 0; i < 5; ++i)
            t6[i] = fmaxf(fmaxf(m16[3 * i], m16[3 * i + 1]), m16[3 * i + 2]);
        t6[5] = m16[15];
        float u0 = fmaxf(fmaxf(t6[0], t6[1]), t6[2]);
        float u1 = fmaxf(fmaxf(t6[3], t6[4]), t6[5]);
        float mx = cross32_max(fmaxf(u0, u1));

        const float mnew = fmaxf(mrun, mx);
        if (!__all(mx - mrun <= 8.0f)) {     // defer-max (THR=8 in log2 units)
            const float corr = exp2_raw(mrun - mnew);
            lrun *= corr;
#pragma unroll
            for (int dblk = 0; dblk < 4; ++dblk)
#pragma unroll
                for (int i = 0; i < 16; ++i) o[dblk][i] *= corr;
            mrun = mnew;
        }
#pragma unroll
        for (int i = 0; i < 16; ++i) { pP0[i] = exp2_raw(pP0[i] - mrun); pP1[i] = exp2_raw(pP1[i] - mrun); }
        float s16[16];
#pragma unroll
        for (int i = 0; i < 16; ++i) s16[i] = pP0[i] + pP1[i];
        float s8[8];
#pragma unroll
        for (int i = 0; i < 8; ++i) s8[i] = s16[2 * i] + s16[2 * i + 1];
        float s4[4];
#pragma unroll
        for (int i = 0; i < 4; ++i) s4[i] = s8[2 * i] + s8[2 * i + 1];
        float ps = (s4[0] + s4[1]) + (s4[2] + s4[3]);
        lrun += cross32_add(ps);

        // P -> bf16 PV A-fragments (T12): swap(A_,C_) = (w0,w2), swap(B_,D_) = (w1,w3)
        short8 pa[4];
#pragma unroll
        for (int b = 0; b < 4; ++b) {
            const int r0 = (b & 1) * 8;
            const float* psrc = (b < 2) ? (const float*)&pP0 : (const float*)&pP1;
            const int A_ = cvt_pk_bf16(psrc[r0 + 0], psrc[r0 + 1]);
            const int B_ = cvt_pk_bf16(psrc[r0 + 2], psrc[r0 + 3]);
            const int C_ = cvt_pk_bf16(psrc[r0 + 4], psrc[r0 + 5]);
            const int D_ = cvt_pk_bf16(psrc[r0 + 6], psrc[r0 + 7]);
            v2i s1 = __builtin_amdgcn_permlane32_swap(A_, C_, false, false);
            v2i s2 = __builtin_amdgcn_permlane32_swap(B_, D_, false, false);
            i32x4 wv; wv.x = s1.x; wv.y = s2.x; wv.z = s1.y; wv.w = s2.y;
            pa[b] = __builtin_bit_cast(short8, wv);
        }

        // ---- PV(t): O^T[d][q] += Vt[d][t] P[t][q] ----
        __builtin_amdgcn_s_setprio(1);
#pragma unroll
        for (int dblk = 0; dblk < 4; ++dblk) {
            const int vrow = dblk * 32 + l31;
            const int vmsk = (vrow ^ (vrow >> 3)) & 7;
#pragma unroll
            for (int ks = 0; ks < 4; ++ks) {
                const int ch = ((ks * 2 + hi) ^ vmsk) * 8;
                short8 vv = *(const short8*)(&Vbuf[vrow * 64 + ch]);
                o[dblk] = __builtin_amdgcn_mfma_f32_32x32x16_bf16(vv, pa[ks], o[dblk], 0, 0, 0);
            }
        }
        __builtin_amdgcn_s_setprio(0);

        __syncthreads();                    // all waves done reading Vbuf
        if (t + 1 < NT) stage_v((t + 1) * 64);   // single-buffer refill

        pP0 = pN0; pP1 = pN1;
    }

    // epilogue: att[q][h*128+d] = O^T[d][q]/lrun ; d = dblk*32 + (2j&3)+8*(j>>1)+4*hi
    const float inv = 1.0f / lrun;
    ushort_t* arow = att + (size_t)qrow * (HEADS * DH) + h * DH;
#pragma unroll
    for (int dblk = 0; dblk < 4; ++dblk)
#pragma unroll
        for (int j = 0; j < 8; ++j) {
            const int d = dblk * 32 + ((2 * j) & 3) + 8 * (j >> 1) + 4 * hi;
            const int pk = cvt_pk_bf16(o[dblk][2 * j] * inv, o[dblk][2 * j + 1] * inv);
            *(int*)(arow + d) = pk;
        }
}

extern "C" void kernel_launch(void* const* d_in, const int* in_sizes, int n_in,
                              void* d_out, int out_size, void* d_ws, size_t ws_size,
                              hipStream_t stream) {
    const float* x  = (const float*)d_in[0];
    const float* Wq = (const float*)d_in[1];
    const float* bq = (const float*)d_in[2];
    const float* Wk = (const float*)d_in[3];
    const float* bk = (const float*)d_in[4];
    const float* Wv = (const float*)d_in[5];
    const float* bv = (const float*)d_in[6];
    const float* Wo = (const float*)d_in[7];
    const float* bo = (const float*)d_in[8];
    float* out = (float*)d_out;

    ushort_t* ws = (ushort_t*)d_ws;
    ushort_t* xp   = ws;
    ushort_t* Wqt  = xp  + (size_t)SEQ * EMB;        // Wqt, Wkt, Wvt contiguous
    ushort_t* Wkt  = Wqt + (size_t)HEADS * DH * EMB;
    ushort_t* Wvt  = Wkt + (size_t)HEADS * DH * EMB;
    ushort_t* Wot  = Wvt + (size_t)HEADS * DH * EMB;
    ushort_t* Qb   = Wot + (size_t)EMB * (HEADS * DH);
    ushort_t* Kb   = Qb  + (size_t)HEADS * SEQ * DH;
    ushort_t* Vtb  = Kb  + (size_t)HEADS * SEQ * DH;
    ushort_t* attb = Vtb + (size_t)HEADS * SEQ * DH;

    prep_x_kernel<<<dim3(SEQ), 256, 0, stream>>>(x, xp);

    transpose_qkv_kernel<<<dim3(EMB / 64, DH / 64, 48), 256, 0, stream>>>(Wq, Wk, Wv, Wqt);
    transpose_w_kernel<<<dim3((HEADS * DH) / 64, EMB / 64, 1), 256, 0, stream>>>(Wo, Wot, HEADS * DH, EMB);

    // Q pre-scaled by SCALE*log2e; K normal; V computed transposed [h][d][s]
    gemm_bias_kernel<4><<<dim3(SEQ / 128, DH / 128, HEADS), 256, 0, stream>>>(xp, Wqt, bq, Qb, SEQ, DH, EMB);
    gemm_bias_kernel<0><<<dim3(SEQ / 128, DH / 128, HEADS), 256, 0, stream>>>(xp, Wkt, bk, Kb, SEQ, DH, EMB);
    gemm_bias_kernel<3><<<dim3(DH / 128, SEQ / 128, HEADS), 256, 0, stream>>>(Wvt, xp, bv, Vtb, DH, SEQ, EMB);

    attn_kernel<<<dim3(SEQ / 128 * HEADS), 256, 0, stream>>>(Qb, Kb, Vtb, attb);

    gemm_bias_kernel<2><<<dim3(SEQ / 128, EMB / 128, 1), 256, 0, stream>>>(attb, Wot, bo, out, SEQ, EMB, HEADS * DH);
}

// Round 19
// 346.110 us; speedup vs baseline: 2.4956x; 1.1001x over previous
//
#include <hip/hip_runtime.h>
#include <hip/hip_bf16.h>

typedef unsigned short ushort_t;
typedef __attribute__((ext_vector_type(8))) short short8;
typedef __attribute__((ext_vector_type(4))) float f32x4;
typedef __attribute__((ext_vector_type(16))) float f32x16;
typedef __attribute__((ext_vector_type(2))) int v2i;
typedef __attribute__((ext_vector_type(4))) int i32x4;

#define SEQ 4096
#define EMB 1024
#define HEADS 16
#define DH 128
#define SCALE_LOG2E 0.12751743f           /* (1/sqrt(128)) * log2(e): scores in log2 domain */

__device__ __forceinline__ ushort_t f2bf(float f) {
    union { float f; unsigned u; } v; v.f = f;
    unsigned r = v.u + 0x7fffu + ((v.u >> 16) & 1u);
    return (ushort_t)(r >> 16);
}

__device__ __forceinline__ int cvt_pk_bf16(float lo, float hi) {
    int r;
    asm("v_cvt_pk_bf16_f32 %0, %1, %2" : "=v"(r) : "v"(lo), "v"(hi));
    return r;
}

__device__ __forceinline__ float exp2_raw(float x) {
    float r;
    asm("v_exp_f32 %0, %1" : "=v"(r) : "v"(x));
    return r;
}

// cross 32-lane-half combine: every lane gets op(x[l], x[l^32])
__device__ __forceinline__ float cross32_max(float x) {
    v2i r = __builtin_amdgcn_permlane32_swap(__float_as_int(x), __float_as_int(x), false, false);
    return fmaxf(__int_as_float(r.x), __int_as_float(r.y));
}
__device__ __forceinline__ float cross32_add(float x) {
    v2i r = __builtin_amdgcn_permlane32_swap(__float_as_int(x), __float_as_int(x), false, false);
    return __int_as_float(r.x) + __int_as_float(r.y);
}

// async global->LDS, 16B per lane; lds base must be wave-uniform (dest = base + lane*16)
__device__ __forceinline__ void gload_lds16(const ushort_t* g, ushort_t* l) {
    __builtin_amdgcn_global_load_lds(
        (const __attribute__((address_space(1))) void*)g,
        (__attribute__((address_space(3))) void*)l, 16, 0, 0);
}

// xp = x + positional_encoding, bf16 out. One block per row; thread handles 4 cols.
// For c >= 10: 10000^expo overflows fp32 -> denom 0 -> pe = (c odd ? 1 : 0) exactly.
__global__ __launch_bounds__(256) void prep_x_kernel(
    const float* __restrict__ x, ushort_t* __restrict__ xp)
{
    const int s = blockIdx.x;
    const int c0 = threadIdx.x * 4;
    const float4 v = *(const float4*)(x + (size_t)s * EMB + c0);
    float pe[4];
    if (c0 >= 10) {
        pe[0] = 0.f; pe[1] = 1.f; pe[2] = 0.f; pe[3] = 1.f;
    } else {
#pragma unroll
        for (int i = 0; i < 4; ++i) {
            const int c = c0 + i;
            float p = powf(10000.0f, (float)(c & ~1));
            float ang = (float)s * ((float)EMB / p);      // inf -> 0 (matches jax fp32)
            pe[i] = (c & 1) ? cosf(ang) : sinf(ang);
        }
    }
    union { ushort_t u[4]; unsigned long long ll; } o;
    o.u[0] = f2bf(v.x + pe[0]); o.u[1] = f2bf(v.y + pe[1]);
    o.u[2] = f2bf(v.z + pe[2]); o.u[3] = f2bf(v.w + pe[3]);
    *(unsigned long long*)(xp + (size_t)s * EMB + c0) = o.ll;
}

// Fused Wq/Wk/Wv transpose: W[h][k][n] f32 -> Wt[(which*16+h)][n][k] bf16 (contiguous dest).
__global__ __launch_bounds__(256) void transpose_qkv_kernel(
    const float* __restrict__ Wq, const float* __restrict__ Wk,
    const float* __restrict__ Wv, ushort_t* __restrict__ Wt)
{
    const int z = blockIdx.z;
    const int which = z >> 4, b = z & 15;
    const float* W = (which == 0) ? Wq : (which == 1) ? Wk : Wv;
    const int k0 = blockIdx.x * 64, n0 = blockIdx.y * 64;
    const int tx = threadIdx.x & 63, ty = threadIdx.x >> 6;
    __shared__ ushort_t t[64][65];
    const float* Wb = W + (size_t)b * EMB * DH;
    ushort_t* Wtb = Wt + (size_t)z * DH * EMB;
#pragma unroll
    for (int i = 0; i < 16; ++i) {
        const int r = ty + i * 4;
        t[r][tx] = f2bf(Wb[(size_t)(k0 + r) * DH + n0 + tx]);
    }
    __syncthreads();
#pragma unroll
    for (int i = 0; i < 16; ++i) {
        const int r = ty + i * 4;
        Wtb[(size_t)(n0 + r) * EMB + k0 + tx] = t[tx][r];
    }
}

// W[b][k][n] f32 -> Wt[b][n][k] bf16, coalesced via 64x64 LDS tile (used for Wo)
__global__ __launch_bounds__(256) void transpose_w_kernel(
    const float* __restrict__ W, ushort_t* __restrict__ Wt, int Kd, int Nd)
{
    const int b = blockIdx.z;
    const int k0 = blockIdx.x * 64, n0 = blockIdx.y * 64;
    const int tx = threadIdx.x & 63, ty = threadIdx.x >> 6;
    __shared__ ushort_t t[64][65];
    const float* Wb = W + (size_t)b * Kd * Nd;
    ushort_t* Wtb = Wt + (size_t)b * Nd * Kd;
#pragma unroll
    for (int i = 0; i < 16; ++i) {
        const int r = ty + i * 4;
        t[r][tx] = f2bf(Wb[(size_t)(k0 + r) * Nd + n0 + tx]);
    }
    __syncthreads();
#pragma unroll
    for (int i = 0; i < 16; ++i) {
        const int r = ty + i * 4;
        Wtb[(size_t)(n0 + r) * Kd + k0 + tx] = t[tx][r];
    }
}

// C = A(bf16, MxK) @ Bt(bf16, NxK)^T + bias, 128x128 tile, 4 waves (2x2), BK=32.
// MODE 0: A shared, Bt per-head; bias[h*N+col]; bf16 out [(h*M+row)*N+col]   (K)
// MODE 4: like MODE 0 but out scaled by SCALE_LOG2E                           (Q)
// MODE 3: A per-head, Bt shared;  bias[h*M+row]; bf16 out [(h*M+row)*N+col]  (V^T)
template <int MODE>
__global__ __launch_bounds__(256) void gemm_bias_kernel(
    const ushort_t* __restrict__ A, const ushort_t* __restrict__ Bt,
    const float* __restrict__ bias, void* __restrict__ Cout,
    int M, int N, int K)
{
    const int mb = blockIdx.x, nb = blockIdx.y, h = blockIdx.z;
    const int tid = threadIdx.x;
    const int w = tid >> 6;
    const int l = tid & 63;
    const int l15 = l & 15, lhi = l >> 4;
    const int wm = w >> 1, wn = w & 1;

    __shared__ ushort_t Abuf[2][128 * 32];
    __shared__ ushort_t Bbuf[2][128 * 32];

    const ushort_t* Ah = (MODE == 3) ? A + (size_t)h * M * K : A;
    const ushort_t* Bh = (MODE == 0 || MODE == 4) ? Bt + (size_t)h * N * K : Bt;

    const int m0 = mb * 128, n0 = nb * 128;

    f32x4 acc[4][4];
#pragma unroll
    for (int f = 0; f < 4; ++f)
#pragma unroll
        for (int g = 0; g < 4; ++g) acc[f][g] = f32x4{0.f, 0.f, 0.f, 0.f};

    const int srow = w * 16 + (l >> 2);
    const int sk = (l & 3) * 8;
    auto stage = [&](int buf, int kt) {
        const int k0 = kt * 32;
#pragma unroll
        for (int i = 0; i < 2; ++i) {
            gload_lds16(Ah + (size_t)(m0 + i * 64 + srow) * K + k0 + sk,
                        &Abuf[buf][(i * 64 + w * 16) * 32]);
            gload_lds16(Bh + (size_t)(n0 + i * 64 + srow) * K + k0 + sk,
                        &Bbuf[buf][(i * 64 + w * 16) * 32]);
        }
    };

    const int nk = K / 32;
    int cur = 0;
    stage(0, 0);
    asm volatile("s_waitcnt vmcnt(0)" ::: "memory");
    __syncthreads();

    for (int kt = 0; kt < nk; ++kt) {
        if (kt + 1 < nk) stage(cur ^ 1, kt + 1);

        short8 af[4], bf[4];
#pragma unroll
        for (int f = 0; f < 4; ++f)
            af[f] = *(const short8*)(&Abuf[cur][(wm * 64 + f * 16 + l15) * 32 + lhi * 8]);
#pragma unroll
        for (int g = 0; g < 4; ++g)
            bf[g] = *(const short8*)(&Bbuf[cur][(wn * 64 + g * 16 + l15) * 32 + lhi * 8]);
#pragma unroll
        for (int f = 0; f < 4; ++f)
#pragma unroll
            for (int g = 0; g < 4; ++g)
                acc[f][g] = __builtin_amdgcn_mfma_f32_16x16x32_bf16(af[f], bf[g], acc[f][g], 0, 0, 0);

        asm volatile("s_waitcnt vmcnt(0)" ::: "memory");
        __syncthreads();
        cur ^= 1;
    }

#pragma unroll
    for (int f = 0; f < 4; ++f) {
        const int row0 = m0 + wm * 64 + f * 16 + 4 * lhi;
#pragma unroll
        for (int g = 0; g < 4; ++g) {
            const int col = n0 + wn * 64 + g * 16 + l15;
            float bv;
            if (MODE == 0 || MODE == 4) bv = bias[(size_t)h * N + col];
            else bv = 0.f;
#pragma unroll
            for (int r = 0; r < 4; ++r) {
                const int row = row0 + r;
                float val = acc[f][g][r];
                if (MODE == 3) val += bias[(size_t)h * M + row];
                else val += bv;
                if (MODE == 4) val *= SCALE_LOG2E;
                ((ushort_t*)Cout)[((size_t)h * M + row) * N + col] = f2bf(val);
            }
        }
    }
}

// Final projection: out = att @ Wot^T + bo, f32 out. 64x128 tile (grid 64x8 = 512
// blocks -> 2 blocks/CU), 4 waves (2x2, 32x64 each), BK=32, dbuf LDS (24 KB).
__global__ __launch_bounds__(256) void final_gemm_kernel(
    const ushort_t* __restrict__ A, const ushort_t* __restrict__ Bt,
    const float* __restrict__ bias, float* __restrict__ out)
{
    const int mb = blockIdx.x, nb = blockIdx.y;
    const int tid = threadIdx.x;
    const int w = tid >> 6, l = tid & 63;
    const int l15 = l & 15, lhi = l >> 4;
    const int wm = w >> 1, wn = w & 1;
    const int K = HEADS * DH;            // 2048

    __shared__ ushort_t Abuf[2][64 * 32];
    __shared__ ushort_t Bbuf[2][128 * 32];

    const int m0 = mb * 64, n0 = nb * 128;

    f32x4 acc[2][4];
#pragma unroll
    for (int f = 0; f < 2; ++f)
#pragma unroll
        for (int g = 0; g < 4; ++g) acc[f][g] = f32x4{0.f, 0.f, 0.f, 0.f};

    const int srowA = tid >> 2;          // 64 rows x 4 chunks
    const int srowB = w * 16 + (l >> 2); // per-64-half rows
    const int sk = (l & 3) * 8;
    auto stage = [&](int buf, int kt) {
        const int k0 = kt * 32;
        gload_lds16(A + (size_t)(m0 + srowA) * K + k0 + sk, &Abuf[buf][(tid >> 2 << 2) * 8]);
#pragma unroll
        for (int i = 0; i < 2; ++i)
            gload_lds16(Bt + (size_t)(n0 + i * 64 + srowB) * K + k0 + sk,
                        &Bbuf[buf][(i * 64 + w * 16) * 32]);
    };

    const int nk = K / 32;
    int cur = 0;
    stage(0, 0);
    asm volatile("s_waitcnt vmcnt(0)" ::: "memory");
    __syncthreads();

    for (int kt = 0; kt < nk; ++kt) {
        if (kt + 1 < nk) stage(cur ^ 1, kt + 1);

        short8 af[2], bf[4];
#pragma unroll
        for (int f = 0; f < 2; ++f)
            af[f] = *(const short8*)(&Abuf[cur][(wm * 32 + f * 16 + l15) * 32 + lhi * 8]);
#pragma unroll
        for (int g = 0; g < 4; ++g)
            bf[g] = *(const short8*)(&Bbuf[cur][(wn * 64 + g * 16 + l15) * 32 + lhi * 8]);
#pragma unroll
        for (int f = 0; f < 2; ++f)
#pragma unroll
            for (int g = 0; g < 4; ++g)
                acc[f][g] = __builtin_amdgcn_mfma_f32_16x16x32_bf16(af[f], bf[g], acc[f][g], 0, 0, 0);

        asm volatile("s_waitcnt vmcnt(0)" ::: "memory");
        __syncthreads();
        cur ^= 1;
    }

#pragma unroll
    for (int f = 0; f < 2; ++f) {
        const int row0 = m0 + wm * 32 + f * 16 + 4 * lhi;
#pragma unroll
        for (int g = 0; g < 4; ++g) {
            const int col = n0 + wn * 64 + g * 16 + l15;
            const float bv = bias[col];
#pragma unroll
            for (int r = 0; r < 4; ++r)
                out[(size_t)(row0 + r) * EMB + col] = acc[f][g][r] + bv;
        }
    }
}

// Flash attention, 32x32 swapped-operand, log2 softmax, XCD-chunked swizzle.
// (round-16 structure: 80 KB LDS, triple-V, single barrier/tile, stage-after-barrier;
//  A/B change this round: ALL s_setprio removed.)
__global__ __launch_bounds__(256) void attn_kernel(
    const ushort_t* __restrict__ Q, const ushort_t* __restrict__ K,
    const ushort_t* __restrict__ Vt, ushort_t* __restrict__ att)
{
    // XCD swizzle: 512 blocks, 8 XCDs, 64 blocks/XCD; major index = head pair
    const int bid = blockIdx.x;
    const int swz = (bid & 7) * 64 + (bid >> 3);   // bijective (512 % 8 == 0)
    const int qb = swz & 31;
    const int h = swz >> 5;

    const int tid = threadIdx.x;
    const int w = tid >> 6;
    const int l = tid & 63;
    const int l31 = l & 31;
    const int hi = l >> 5;

    __shared__ ushort_t Kbuf[2][64 * 128];   // [t][d]
    __shared__ ushort_t Vbuf[3][128 * 64];   // [d][t]

    const ushort_t* Qh = Q + (size_t)h * SEQ * DH;
    const ushort_t* Kh = K + (size_t)h * SEQ * DH;
    const ushort_t* Vh = Vt + (size_t)h * DH * SEQ;

    const int qrow = qb * 128 + w * 32 + l31;
    short8 qf[8];
#pragma unroll
    for (int c = 0; c < 8; ++c)
        qf[c] = *(const short8*)(Qh + (size_t)qrow * DH + c * 16 + hi * 8);

    f32x16 o[4];
#pragma unroll
    for (int dblk = 0; dblk < 4; ++dblk)
#pragma unroll
        for (int i = 0; i < 16; ++i) o[dblk][i] = 0.f;
    float mrun = -1e30f, lrun = 0.f;

    auto stage_k = [&](int buf, int t0) {
#pragma unroll
        for (int i = 0; i < 4; ++i) {
            const int L = i * 256 + tid;
            const int row = L >> 4;
            const int c = (L & 15) ^ ((row ^ (row >> 3)) & 15);
            gload_lds16(Kh + (size_t)(t0 + row) * DH + c * 8,
                        &Kbuf[buf][(L & ~63) * 8]);
        }
    };
    auto stage_v = [&](int buf, int t0) {
#pragma unroll
        for (int i = 0; i < 4; ++i) {
            const int L = i * 256 + tid;
            const int row = L >> 3;
            const int c = (L & 7) ^ ((row ^ (row >> 3)) & 7);
            gload_lds16(Vh + (size_t)row * SEQ + t0 + c * 8,
                        &Vbuf[buf][(L & ~63) * 8]);
        }
    };

    const int kmsk0 = (l31 ^ (l31 >> 3)) & 15;
    const int r1row = 32 + l31;
    const int kmsk1 = (r1row ^ (r1row >> 3)) & 15;

    // prologue: tile 0 landed; tile 1 in flight; QK^T(0) computed
    stage_k(0, 0); stage_v(0, 0);
    asm volatile("s_waitcnt vmcnt(0)" ::: "memory");
    __syncthreads();
    stage_k(1, 64); stage_v(1, 64);

    f32x16 pP0, pP1, pN0, pN1;
#pragma unroll
    for (int i = 0; i < 16; ++i) { pP0[i] = 0.f; pP1[i] = 0.f; pN0[i] = 0.f; pN1[i] = 0.f; }
#pragma unroll
    for (int c = 0; c < 8; ++c) {
        short8 k0 = *(const short8*)(&Kbuf[0][l31 * 128 + ((c * 2 + hi) ^ kmsk0) * 8]);
        pP0 = __builtin_amdgcn_mfma_f32_32x32x16_bf16(k0, qf[c], pP0, 0, 0, 0);
        short8 k1 = *(const short8*)(&Kbuf[0][r1row * 128 + ((c * 2 + hi) ^ kmsk1) * 8]);
        pP1 = __builtin_amdgcn_mfma_f32_32x32x16_bf16(k1, qf[c], pP1, 0, 0, 0);
    }

    const int NT = SEQ / 64;
    int vt = 0;                          // Vbuf index of tile t (t % 3)
    for (int t = 0; t < NT; ++t) {
        const int vt2 = (vt >= 1) ? vt - 1 : vt + 2;   // (t+2) % 3

        asm volatile("s_waitcnt vmcnt(0)" ::: "memory");   // tile t+1 landed
        __syncthreads();                                    // all waves done with t-1 bufs

        if (t + 2 < NT) {                // stage t+2 NOW: full iteration to land
            stage_k(t & 1, (t + 2) * 64);
            stage_v(vt2, (t + 2) * 64);
        }

        if (t + 1 < NT) {
            // QK^T(t+1) -> pN (MFMA; overlaps softmax(t) VALU below)
#pragma unroll
            for (int i = 0; i < 16; ++i) { pN0[i] = 0.f; pN1[i] = 0.f; }
#pragma unroll
            for (int c = 0; c < 8; ++c) {
                short8 k0 = *(const short8*)(&Kbuf[(t + 1) & 1][l31 * 128 + ((c * 2 + hi) ^ kmsk0) * 8]);
                pN0 = __builtin_amdgcn_mfma_f32_32x32x16_bf16(k0, qf[c], pN0, 0, 0, 0);
                short8 k1 = *(const short8*)(&Kbuf[(t + 1) & 1][r1row * 128 + ((c * 2 + hi) ^ kmsk1) * 8]);
                pN1 = __builtin_amdgcn_mfma_f32_32x32x16_bf16(k1, qf[c], pN1, 0, 0, 0);
            }
        }

        // ---- softmax(t) on pP (VALU; log2 domain); max via v_max3 nests ----
        float m16[16];
#pragma unroll
        for (int i = 0; i < 16; ++i) m16[i] = fmaxf(pP0[i], pP1[i]);
        float t6[6];
#pragma unroll
        for (int i = 0; i < 5; ++i)
            t6[i] = fmaxf(fmaxf(m16[3 * i], m16[3 * i + 1]), m16[3 * i + 2]);
        t6[5] = m16[15];
        float u0 = fmaxf(fmaxf(t6[0], t6[1]), t6[2]);
        float u1 = fmaxf(fmaxf(t6[3], t6[4]), t6[5]);
        float mx = cross32_max(fmaxf(u0, u1));

        const float mnew = fmaxf(mrun, mx);
        if (!__all(mx - mrun <= 8.0f)) {     // defer-max (THR=8 in log2 units)
            const float corr = exp2_raw(mrun - mnew);
            lrun *= corr;
#pragma unroll
            for (int dblk = 0; dblk < 4; ++dblk)
#pragma unroll
                for (int i = 0; i < 16; ++i) o[dblk][i] *= corr;
            mrun = mnew;
        }
#pragma unroll
        for (int i = 0; i < 16; ++i) { pP0[i] = exp2_raw(pP0[i] - mrun); pP1[i] = exp2_raw(pP1[i] - mrun); }
        float s16[16];
#pragma unroll
        for (int i = 0; i < 16; ++i) s16[i] = pP0[i] + pP1[i];
        float s8[8];
#pragma unroll
        for (int i = 0; i < 8; ++i) s8[i] = s16[2 * i] + s16[2 * i + 1];
        float s4[4];
#pragma unroll
        for (int i = 0; i < 4; ++i) s4[i] = s8[2 * i] + s8[2 * i + 1];
        float ps = (s4[0] + s4[1]) + (s4[2] + s4[3]);
        lrun += cross32_add(ps);

        // P -> bf16 PV A-fragments (T12): swap(A_,C_) = (w0,w2), swap(B_,D_) = (w1,w3)
        short8 pa[4];
#pragma unroll
        for (int b = 0; b < 4; ++b) {
            const int r0 = (b & 1) * 8;
            const float* psrc = (b < 2) ? (const float*)&pP0 : (const float*)&pP1;
            const int A_ = cvt_pk_bf16(psrc[r0 + 0], psrc[r0 + 1]);
            const int B_ = cvt_pk_bf16(psrc[r0 + 2], psrc[r0 + 3]);
            const int C_ = cvt_pk_bf16(psrc[r0 + 4], psrc[r0 + 5]);
            const int D_ = cvt_pk_bf16(psrc[r0 + 6], psrc[r0 + 7]);
            v2i s1 = __builtin_amdgcn_permlane32_swap(A_, C_, false, false);
            v2i s2 = __builtin_amdgcn_permlane32_swap(B_, D_, false, false);
            i32x4 wv; wv.x = s1.x; wv.y = s2.x; wv.z = s1.y; wv.w = s2.y;
            pa[b] = __builtin_bit_cast(short8, wv);
        }

        // ---- PV(t): O^T[d][q] += Vt[d][t] P[t][q] ----
#pragma unroll
        for (int dblk = 0; dblk < 4; ++dblk) {
            const int vrow = dblk * 32 + l31;
            const int vmsk = (vrow ^ (vrow >> 3)) & 7;
#pragma unroll
            for (int ks = 0; ks < 4; ++ks) {
                const int ch = ((ks * 2 + hi) ^ vmsk) * 8;
                short8 vv = *(const short8*)(&Vbuf[vt][vrow * 64 + ch]);
                o[dblk] = __builtin_amdgcn_mfma_f32_32x32x16_bf16(vv, pa[ks], o[dblk], 0, 0, 0);
            }
        }

        pP0 = pN0; pP1 = pN1;
        vt = (vt >= 2) ? 0 : vt + 1;
    }

    // epilogue: att[q][h*128+d] = O^T[d][q]/lrun ; d = dblk*32 + (2j&3)+8*(j>>1)+4*hi
    const float inv = 1.0f / lrun;
    ushort_t* arow = att + (size_t)qrow * (HEADS * DH) + h * DH;
#pragma unroll
    for (int dblk = 0; dblk < 4; ++dblk)
#pragma unroll
        for (int j = 0; j < 8; ++j) {
            const int d = dblk * 32 + ((2 * j) & 3) + 8 * (j >> 1) + 4 * hi;
            const int pk = cvt_pk_bf16(o[dblk][2 * j] * inv, o[dblk][2 * j + 1] * inv);
            *(int*)(arow + d) = pk;
        }
}

extern "C" void kernel_launch(void* const* d_in, const int* in_sizes, int n_in,
                              void* d_out, int out_size, void* d_ws, size_t ws_size,
                              hipStream_t stream) {
    const float* x  = (const float*)d_in[0];
    const float* Wq = (const float*)d_in[1];
    const float* bq = (const float*)d_in[2];
    const float* Wk = (const float*)d_in[3];
    const float* bk = (const float*)d_in[4];
    const float* Wv = (const float*)d_in[5];
    const float* bv = (const float*)d_in[6];
    const float* Wo = (const float*)d_in[7];
    const float* bo = (const float*)d_in[8];
    float* out = (float*)d_out;

    ushort_t* ws = (ushort_t*)d_ws;
    ushort_t* xp   = ws;
    ushort_t* Wqt  = xp  + (size_t)SEQ * EMB;        // Wqt, Wkt, Wvt contiguous
    ushort_t* Wkt  = Wqt + (size_t)HEADS * DH * EMB;
    ushort_t* Wvt  = Wkt + (size_t)HEADS * DH * EMB;
    ushort_t* Wot  = Wvt + (size_t)HEADS * DH * EMB;
    ushort_t* Qb   = Wot + (size_t)EMB * (HEADS * DH);
    ushort_t* Kb   = Qb  + (size_t)HEADS * SEQ * DH;
    ushort_t* Vtb  = Kb  + (size_t)HEADS * SEQ * DH;
    ushort_t* attb = Vtb + (size_t)HEADS * SEQ * DH;

    prep_x_kernel<<<dim3(SEQ), 256, 0, stream>>>(x, xp);

    transpose_qkv_kernel<<<dim3(EMB / 64, DH / 64, 48), 256, 0, stream>>>(Wq, Wk, Wv, Wqt);
    transpose_w_kernel<<<dim3((HEADS * DH) / 64, EMB / 64, 1), 256, 0, stream>>>(Wo, Wot, HEADS * DH, EMB);

    // Q pre-scaled by SCALE*log2e; K normal; V computed transposed [h][d][s]
    gemm_bias_kernel<4><<<dim3(SEQ / 128, DH / 128, HEADS), 256, 0, stream>>>(xp, Wqt, bq, Qb, SEQ, DH, EMB);
    gemm_bias_kernel<0><<<dim3(SEQ / 128, DH / 128, HEADS), 256, 0, stream>>>(xp, Wkt, bk, Kb, SEQ, DH, EMB);
    gemm_bias_kernel<3><<<dim3(DH / 128, SEQ / 128, HEADS), 256, 0, stream>>>(Wvt, xp, bv, Vtb, DH, SEQ, EMB);

    attn_kernel<<<dim3(SEQ / 128 * HEADS), 256, 0, stream>>>(Qb, Kb, Vtb, attb);

    final_gemm_kernel<<<dim3(SEQ / 64, EMB / 128), 256, 0, stream>>>(attb, Wot, bo, out);
}